// Round 1
// baseline (274.988 us; speedup 1.0000x reference)
//
#include <hip/hip_runtime.h>
#include <hip/hip_bf16.h>
#include <math.h>

typedef short s16x8 __attribute__((ext_vector_type(8)));
typedef float f32x4 __attribute__((ext_vector_type(4)));

__device__ inline ushort f2bf(float f) {
  unsigned u = __float_as_uint(f);
  u = (u + 0x7FFF + ((u >> 16) & 1)) >> 16;
  return (ushort)u;
}
__device__ inline float bf2f(ushort u) {
  return __uint_as_float(((unsigned)u) << 16);
}
// packed f32x2 -> bf16x2 RNE (bit-identical to f2bf pair)
__device__ inline unsigned pkbf(float a, float b) {
  __hip_bfloat162 h = __float22bfloat162_rn(make_float2(a, b));
  return *(unsigned*)&h;
}
// bf16 pair unpack from a dword: low half / high half (bit-identical to bf2f)
__device__ inline float bflo(unsigned u) { return __uint_as_float(u << 16); }
__device__ inline float bfhi(unsigned u) { return __uint_as_float(u & 0xffff0000u); }
// fast activations: v_exp_f32 + v_rcp_f32; saturate correctly at +/-inf.
__device__ inline float fast_tanh(float v) {
  float e = __builtin_amdgcn_exp2f(v * 2.8853900817779268f);   // exp(2v)
  return 1.f - 2.f * __builtin_amdgcn_rcpf(e + 1.f);
}
__device__ inline float fast_sigmoid(float v) {
  float e = __builtin_amdgcn_exp2f(v * -1.4426950408889634f);  // exp(-v)
  return __builtin_amdgcn_rcpf(1.f + e);
}

// ---- PERMUTED head-row space (640 rows):
//   g in [0,18): off | [18,27): mod | [27,64): pad | [64,640): col j=g-64=k*64+c
//     source col channel cc = c*9+k.
// ---- K0: pack weights into MFMA-fragment order in permuted row space ------------------
// Wpk[og 5][ks 18][ocq 2][mi 4][lane 64][e 8]; W2pk[ks 18][mi 4][lane 64][e 8].
__global__ __launch_bounds__(256) void k_merge(
    const float* __restrict__ wp, const float* __restrict__ bp,
    const float* __restrict__ wm, const float* __restrict__ bm,
    const float* __restrict__ wc, const float* __restrict__ bc,
    const float* __restrict__ wconv,
    ushort* __restrict__ Wpk, float* __restrict__ Bc, ushort* __restrict__ W2pk) {
  int i = blockIdx.x * 256 + threadIdx.x;
  if (i < 368640) {
    int e = i & 7, lane = (i >> 3) & 63, mi = (i >> 9) & 3, ocq = (i >> 11) & 1;
    int hi = i >> 12;                 // 0..89
    int ks = hi % 18, og = hi / 18;
    int g = og * 128 + ocq * 64 + mi * 16 + (lane & 15);
    int ci = ((ks & 1) << 5) + ((lane >> 4) << 3) + e;
    int kk = ks >> 1;
    int col = ci * 9 + kk;
    float v = 0.f;
    if (g < 18)       v = wp[g * 576 + col];
    else if (g < 27)  v = wm[(g - 18) * 576 + col];
    else if (g >= 64) {
      int j = g - 64;
      int cc = (j & 63) * 9 + (j >> 6);
      v = wc[cc * 576 + col];
    }
    Wpk[i] = f2bf(v);
  }
  if (i < 36864) {
    int e = i & 7, lane = (i >> 3) & 63, mi = (i >> 9) & 3, ks = i >> 11;  // 0..17
    int o = mi * 16 + (lane & 15);
    int p = (ks << 5) + ((lane >> 4) << 3) + e;
    int kk2 = p >> 6, c = p & 63;
    W2pk[i] = f2bf(wconv[o * 576 + c * 9 + kk2]);
  }
  if (i < 640) {
    float bv = 0.f;
    if (i < 18)       bv = bp[i];
    else if (i < 27)  bv = bm[i - 18];
    else if (i >= 64) {
      int j = i - 64;
      bv = bc[(j & 63) * 9 + (j >> 6)];
    }
    Bc[i] = bv;
  }
}

// ---- K1: fused = 1x1 conv -> fusedt[pix][64] bf16, PLUS xtb transpose (folded k_xt) ---
// 4 thr/px x 16 oc; x tile staged once in LDS and reused for both outputs.
__global__ __launch_bounds__(256) void k_fused(
    const float* __restrict__ x, const float* __restrict__ ref,
    const float* __restrict__ wcd, const float* __restrict__ bcd,
    ushort* __restrict__ fusedt, ushort* __restrict__ xtb) {
  __shared__ float sw[128 * 64];
  __shared__ float sx[64][65];
  __shared__ float sb[64];
  const int t = threadIdx.x;
  for (int i = t; i < 128 * 64; i += 256) {
    int ci = i >> 6, o = i & 63;
    sw[i] = wcd[o * 128 + ci];
  }
  if (t < 64) sb[t] = bcd[t];
  const int b = blockIdx.x >> 8, hw0 = (blockIdx.x & 255) << 6;
  for (int i = t; i < 4096; i += 256) {
    int c = i >> 6, hwi = i & 63;
    sx[c][hwi] = x[((size_t)((b << 6) + c) << 14) + hw0 + hwi];
  }
  __syncthreads();

  // xtb[b][hw][c] bf16 pixel-major (reads sx only; no hazard with GEMM reads below)
  for (int i = t * 2; i < 4096; i += 512) {
    int hwi = i >> 6, c = i & 63;    // c even
    unsigned pk = pkbf(sx[c][hwi], sx[c + 1][hwi]);
    *(unsigned*)(xtb + (((size_t)b << 14) + hw0 + hwi) * 64 + c) = pk;
  }

  const int pxi = t & 63, oq = t >> 6;      // wave-uniform oq -> LDS broadcast
  const int pix = blockIdx.x * 64 + pxi;
  const float* rb = ref + (((size_t)b << 6) << 14) + hw0 + pxi;

  float4 acc[4];
  #pragma unroll
  for (int q = 0; q < 4; q++)
    acc[q] = *(const float4*)&sb[oq * 16 + 4 * q];

  for (int ci = 0; ci < 64; ci++) {
    float v = sx[ci][pxi];
    const float4* wr = (const float4*)&sw[ci * 64 + oq * 16];
    #pragma unroll
    for (int q = 0; q < 4; q++) {
      float4 w4 = wr[q];
      acc[q].x += w4.x * v; acc[q].y += w4.y * v;
      acc[q].z += w4.z * v; acc[q].w += w4.w * v;
    }
  }
  for (int ci = 0; ci < 64; ci++) {
    float v = rb[(size_t)ci << 14];
    const float4* wr = (const float4*)&sw[(64 + ci) * 64 + oq * 16];
    #pragma unroll
    for (int q = 0; q < 4; q++) {
      float4 w4 = wr[q];
      acc[q].x += w4.x * v; acc[q].y += w4.y * v;
      acc[q].z += w4.z * v; acc[q].w += w4.w * v;
    }
  }
  uint4 o0, o1;
  o0.x = pkbf(acc[0].x, acc[0].y); o0.y = pkbf(acc[0].z, acc[0].w);
  o0.z = pkbf(acc[1].x, acc[1].y); o0.w = pkbf(acc[1].z, acc[1].w);
  o1.x = pkbf(acc[2].x, acc[2].y); o1.y = pkbf(acc[2].z, acc[2].w);
  o1.z = pkbf(acc[3].x, acc[3].y); o1.w = pkbf(acc[3].z, acc[3].w);
  ushort* fb = fusedt + ((size_t)pix << 6) + oq * 16;
  *(uint4*)fb       = o0;
  *(uint4*)(fb + 8) = o1;
}

// ---- K3: FULLY FUSED head-GEMM + sampler + final GEMM, 64-px tiles --------------------
// grid 1024; block 256 = 4 waves; LDS 48,640B -> 3 blocks/CU (same as measured before).
// Changes vs prev: invariant sF/colT offsets precomputed in regs (reused by all 10
// GEMMs); wave-uniform weight bases via readfirstlane (scalar addressing); packed
// bf16 converts (pkbf/bflo/bfhi); colT double-buffered -> 2 barriers/k instead of 3;
// off/mod GEMM rebalanced across all 4 waves.
__global__ __launch_bounds__(256, 3) void k_all(
    const ushort* __restrict__ Wpk, const ushort* __restrict__ fusedt,
    const float* __restrict__ Bc, const ushort* __restrict__ xtb,
    const ushort* __restrict__ W2pk, float* __restrict__ out) {
  __shared__ __align__(16) ushort sF[3 * 66 * 64];    // 25,344 B
  __shared__ __align__(16) ushort colT[2 * 64 * 64];  // 16,384 B (double buffer)
  __shared__ float homT[64 * 27];                     //  6,912 B
  const int t = threadIdx.x;
  const int lane = t & 63, wv = t >> 6;
  const int rowid = blockIdx.x;           // b*256 + h*2 + half
  const int b = rowid >> 8;
  const int rem = rowid & 255;
  const int h = rem >> 1, hf = rem & 1;
  const int w0 = hf << 6;
  const int hw0 = (h << 7) + w0;

  // stage fused rows h-1..h+1, w1 in [0,66) covering gw in [w0-1, w0+64]
  for (int idx = t; idx < 1584; idx += 256) {   // 198 pixels x 8 ci-chunks
    int p = idx >> 3, j = idx & 7;
    int row = p / 66, w1 = p - row * 66;
    int gh = h + row - 1, gw = w0 + w1 - 1;
    uint4 v = make_uint4(0u, 0u, 0u, 0u);
    if (gh >= 0 && gh < 128 && (unsigned)gw < 128u)
      v = *(const uint4*)(fusedt + ((size_t)((b << 14) + (gh << 7) + gw) << 6) + j * 8);
    int slot = (j + w1) & 7;
    *(uint4*)(sF + (p << 6) + slot * 8) = v;
  }

  const int pxq = wv & 1, rowq = wv >> 1;
  const int nif = lane & 15, kb = lane >> 4, quad = lane >> 4;
  const int wlaneoff = lane << 3;                          // element offset in weight row
  const int rfq = __builtin_amdgcn_readfirstlane(rowq);    // wave-uniform -> SGPR
  const int rowel9  = rfq << 9;                            // off/mod af offset (mi=rowq)
  const int rowel10 = rfq << 10;                           // col/final af base

  // invariant sF read offsets (ushort elements): reused by all 10 head GEMMs
  int sfo[18][2];
  #pragma unroll
  for (int ks = 0; ks < 18; ks++) {
    const int kk = ks >> 1, half = ks & 1;
    const int dr = kk / 3, dc = kk - dr * 3;
    const int gci = half * 4 + kb;
    #pragma unroll
    for (int ni = 0; ni < 2; ni++) {
      const int r = (pxq << 5) + ni * 16 + nif;
      const int w1 = r + dc;
      sfo[ks][ni] = ((dr * 66 + w1) << 6) + (((gci + w1) & 7) << 3);
    }
  }
  // invariant colT read offsets for the final GEMM
  int cto[2][2];
  #pragma unroll
  for (int khalf = 0; khalf < 2; khalf++) {
    const int g0 = (khalf << 2) + kb;
    #pragma unroll
    for (int ni = 0; ni < 2; ni++) {
      const int r = (pxq << 5) + ni * 16 + nif;
      cto[khalf][ni] = (r << 6) + (((g0 + r) & 7) << 3);
    }
  }

  __syncthreads();

  // ---- off/mod GEMM: wave (rowq,pxq) computes rows rowq*16..+16 of its 32 px ----
  {
    f32x4 acc[2];
    acc[0] = (f32x4){0.f, 0.f, 0.f, 0.f};
    acc[1] = (f32x4){0.f, 0.f, 0.f, 0.f};
    #pragma unroll
    for (int ks = 0; ks < 18; ks++) {
      s16x8 af = *(const s16x8*)(Wpk + (ks << 12) + rowel9 + wlaneoff);
      s16x8 b0 = *(const s16x8*)(sF + sfo[ks][0]);
      s16x8 b1 = *(const s16x8*)(sF + sfo[ks][1]);
      acc[0] = __builtin_amdgcn_mfma_f32_16x16x32_bf16(af, b0, acc[0], 0, 0, 0);
      acc[1] = __builtin_amdgcn_mfma_f32_16x16x32_bf16(af, b1, acc[1], 0, 0, 0);
    }
    const float4 b4 = *(const float4*)(Bc + (rowq << 4) + (quad << 2));
    const float bb[4] = {b4.x, b4.y, b4.z, b4.w};
    #pragma unroll
    for (int ni = 0; ni < 2; ni++) {
      const int px = (pxq << 5) + ni * 16 + nif;
      #pragma unroll
      for (int r = 0; r < 4; r++) {
        const int g = (rowq << 4) + (quad << 2) + r;
        float v = acc[ni][r] + bb[r];
        if (g < 18)       homT[px * 27 + g] = v;
        else if (g < 27)  homT[px * 27 + g] = fast_sigmoid(v);
      }
    }
  }

  // sampler per-pixel identity: 4 thr/px x 16 ch (wv = channel quad, lane = pixel)
  const int c0 = wv << 4;
  const int ww = w0 + lane;
  const ushort* xbc = xtb + ((size_t)b << 20) + c0;

  f32x4 aco[2][2];
  #pragma unroll
  for (int mi = 0; mi < 2; mi++)
    #pragma unroll
    for (int ni = 0; ni < 2; ni++) aco[mi][ni] = (f32x4){0.f, 0.f, 0.f, 0.f};

  #pragma unroll 1
  for (int k = 0; k < 9; k++) {
    ushort* ctk = colT + ((k & 1) << 12);   // double buffer

    // ---- col GEMM for this k: permuted rows 64+k*64 .. 128+k*64 ----
    const int q = 1 + k, og = q >> 1, ocq = q & 1;
    const ushort* wb = Wpk + ((size_t)(((og * 36) + ocq) << 11)) + rowel10 + wlaneoff;
    f32x4 acc[2][2];
    #pragma unroll
    for (int mi = 0; mi < 2; mi++)
      #pragma unroll
      for (int ni = 0; ni < 2; ni++) acc[mi][ni] = (f32x4){0.f, 0.f, 0.f, 0.f};
    #pragma unroll
    for (int ks = 0; ks < 18; ks++) {
      const ushort* wp8 = wb + (ks << 12);
      s16x8 af0 = *(const s16x8*)(wp8);
      s16x8 af1 = *(const s16x8*)(wp8 + 512);
      s16x8 b0 = *(const s16x8*)(sF + sfo[ks][0]);
      s16x8 b1 = *(const s16x8*)(sF + sfo[ks][1]);
      acc[0][0] = __builtin_amdgcn_mfma_f32_16x16x32_bf16(af0, b0, acc[0][0], 0, 0, 0);
      acc[0][1] = __builtin_amdgcn_mfma_f32_16x16x32_bf16(af0, b1, acc[0][1], 0, 0, 0);
      acc[1][0] = __builtin_amdgcn_mfma_f32_16x16x32_bf16(af1, b0, acc[1][0], 0, 0, 0);
      acc[1][1] = __builtin_amdgcn_mfma_f32_16x16x32_bf16(af1, b1, acc[1][1], 0, 0, 0);
    }

    // epilogue: tanh -> ctk (slot-rotated); ctk buffer is free (last read at k-2)
    #pragma unroll
    for (int mi = 0; mi < 2; mi++) {
      const int c = (rowq << 5) + mi * 16 + (quad << 2);
      const float4 b4 = *(const float4*)(Bc + 64 + (k << 6) + c);
      #pragma unroll
      for (int ni = 0; ni < 2; ni++) {
        const int px = (pxq << 5) + ni * 16 + nif;
        uint2 pk2;
        pk2.x = pkbf(fast_tanh(acc[mi][ni][0] + b4.x), fast_tanh(acc[mi][ni][1] + b4.y));
        pk2.y = pkbf(fast_tanh(acc[mi][ni][2] + b4.z), fast_tanh(acc[mi][ni][3] + b4.w));
        const int slot = ((c >> 3) + px) & 7;
        *(uint2*)(ctk + (px << 6) + slot * 8 + (c & 7)) = pk2;
      }
    }
    __syncthreads();   // B1: colT[k&1] (+ homT at k=0) visible to sampler

    // ---- sampler: 16 channels of pixel `lane`, in-place update of ctk ----
    {
      const int hb = lane * 27;
      float ox = homT[hb + k];
      float oy = homT[hb + 9 + k];
      float mk = homT[hb + 18 + k];
      const int kdr = k / 3, kdc = k - kdr * 3;
      float px_ = (float)(h + kdr) + ox;
      float py_ = (float)(ww + kdc) + oy;
      float fx = floorf(px_), fy = floorf(py_);
      float qltx = fminf(fmaxf(fx, 0.f), 129.f);
      float qlty = fminf(fmaxf(fy, 0.f), 129.f);
      float qrbx = fminf(fmaxf(fx + 1.f, 0.f), 129.f);
      float qrby = fminf(fmaxf(fy + 1.f, 0.f), 129.f);
      float sx = fminf(fmaxf(px_, 0.f), 129.f);
      float sy = fminf(fmaxf(py_, 0.f), 129.f);
      float ax = 1.f + qltx - sx, bx = 1.f - qrbx + sx;
      float ay = 1.f + qlty - sy, by = 1.f - qrby + sy;
      int iltx = (int)qltx, ilty = (int)qlty, irbx = (int)qrbx, irby = (int)qrby;
      bool vltx = (iltx >= 1) && (iltx <= 128);
      bool vlty = (ilty >= 1) && (ilty <= 128);
      bool vrbx = (irbx >= 1) && (irbx <= 128);
      bool vrby = (irby >= 1) && (irby <= 128);
      float wl[4];
      int   ofs[4];
      wl[0] = (vltx && vlty) ? ax * ay : 0.f;
      wl[1] = (vrbx && vrby) ? bx * by : 0.f;
      wl[2] = (vltx && vrby) ? ax * by : 0.f;
      wl[3] = (vrbx && vlty) ? bx * ay : 0.f;
      ofs[0] = (vltx && vlty) ? ((iltx - 1) << 7) + (ilty - 1) : 0;
      ofs[1] = (vrbx && vrby) ? ((irbx - 1) << 7) + (irby - 1) : 0;
      ofs[2] = (vltx && vrby) ? ((iltx - 1) << 7) + (irby - 1) : 0;
      ofs[3] = (vrbx && vlty) ? ((irbx - 1) << 7) + (ilty - 1) : 0;

      float pos[16];
      #pragma unroll
      for (int j = 0; j < 16; j++) pos[j] = 0.f;
      #pragma unroll
      for (int corner = 0; corner < 4; corner++) {
        const ushort* p = xbc + ((size_t)ofs[corner] << 6);
        uint4 A  = *(const uint4*)(p);
        uint4 Bv = *(const uint4*)(p + 8);
        float wgt = wl[corner];
        pos[0]  += wgt * bflo(A.x);  pos[1]  += wgt * bfhi(A.x);
        pos[2]  += wgt * bflo(A.y);  pos[3]  += wgt * bfhi(A.y);
        pos[4]  += wgt * bflo(A.z);  pos[5]  += wgt * bfhi(A.z);
        pos[6]  += wgt * bflo(A.w);  pos[7]  += wgt * bfhi(A.w);
        pos[8]  += wgt * bflo(Bv.x); pos[9]  += wgt * bfhi(Bv.x);
        pos[10] += wgt * bflo(Bv.y); pos[11] += wgt * bfhi(Bv.y);
        pos[12] += wgt * bflo(Bv.z); pos[13] += wgt * bfhi(Bv.z);
        pos[14] += wgt * bflo(Bv.w); pos[15] += wgt * bfhi(Bv.w);
      }
      // read own col slots, update, write back (thread-exclusive -> no barrier)
      #pragma unroll
      for (int q2 = 0; q2 < 2; q2++) {
        const int chunk = (wv << 1) + q2;
        const int slot = (chunk + lane) & 7;
        ushort* cp = ctk + (lane << 6) + slot * 8;
        uint4 cw = *(const uint4*)cp;
        float f0 = bflo(cw.x) + pos[q2 * 8 + 0];
        float f1 = bfhi(cw.x) + pos[q2 * 8 + 1];
        float f2 = bflo(cw.y) + pos[q2 * 8 + 2];
        float f3 = bfhi(cw.y) + pos[q2 * 8 + 3];
        float f4 = bflo(cw.z) + pos[q2 * 8 + 4];
        float f5 = bfhi(cw.z) + pos[q2 * 8 + 5];
        float f6 = bflo(cw.w) + pos[q2 * 8 + 6];
        float f7 = bfhi(cw.w) + pos[q2 * 8 + 7];
        uint4 ow;
        ow.x = pkbf(f0 * mk, f1 * mk);
        ow.y = pkbf(f2 * mk, f3 * mk);
        ow.z = pkbf(f4 * mk, f5 * mk);
        ow.w = pkbf(f6 * mk, f7 * mk);
        *(uint4*)cp = ow;
      }
    }
    __syncthreads();   // B2: updated ctk visible to MFMA

    // ---- final-GEMM MFMA: 2 ks-steps over this k-tile ----
    #pragma unroll
    for (int khalf = 0; khalf < 2; khalf++) {
      const int ks2 = (k << 1) + khalf;
      const ushort* w2 = W2pk + (ks2 << 11) + rowel10 + wlaneoff;
      s16x8 af0 = *(const s16x8*)(w2);
      s16x8 af1 = *(const s16x8*)(w2 + 512);
      s16x8 b0 = *(const s16x8*)(ctk + cto[khalf][0]);
      s16x8 b1 = *(const s16x8*)(ctk + cto[khalf][1]);
      aco[0][0] = __builtin_amdgcn_mfma_f32_16x16x32_bf16(af0, b0, aco[0][0], 0, 0, 0);
      aco[0][1] = __builtin_amdgcn_mfma_f32_16x16x32_bf16(af0, b1, aco[0][1], 0, 0, 0);
      aco[1][0] = __builtin_amdgcn_mfma_f32_16x16x32_bf16(af1, b0, aco[1][0], 0, 0, 0);
      aco[1][1] = __builtin_amdgcn_mfma_f32_16x16x32_bf16(af1, b1, aco[1][1], 0, 0, 0);
    }
  }

  // ---- store out ----
  #pragma unroll
  for (int mi = 0; mi < 2; mi++) {
    #pragma unroll
    for (int ni = 0; ni < 2; ni++) {
      int hwp = hw0 + (pxq << 5) + ni * 16 + nif;
      #pragma unroll
      for (int r = 0; r < 4; r++) {
        int o = (rowq << 5) + mi * 16 + (quad << 2) + r;
        out[(((size_t)b * 64 + o) << 14) + hwp] = aco[mi][ni][r];
      }
    }
  }
}

extern "C" void kernel_launch(void* const* d_in, const int* in_sizes, int n_in,
                              void* d_out, int out_size, void* d_ws, size_t ws_size,
                              hipStream_t stream) {
  const float* x     = (const float*)d_in[0];
  const float* ref   = (const float*)d_in[1];
  const float* wcd   = (const float*)d_in[2];
  const float* bcd   = (const float*)d_in[3];
  const float* wp    = (const float*)d_in[4];
  const float* bp    = (const float*)d_in[5];
  const float* wm    = (const float*)d_in[6];
  const float* bm    = (const float*)d_in[7];
  const float* wc    = (const float*)d_in[8];
  const float* bc    = (const float*)d_in[9];
  const float* wconv = (const float*)d_in[10];
  float* out = (float*)d_out;

  char* w8 = (char*)d_ws;
  ushort* Wpk     = (ushort*)(w8 + 0);           //    737,280 B
  float*  Bc      = (float*)(w8 + 737280);       //      2,560 B
  ushort* W2pk    = (ushort*)(w8 + 739840);      //     73,728 B
  ushort* fusedt  = (ushort*)(w8 + 813568);      //  8,388,608 B (pixel-major)
  ushort* xtb     = (ushort*)(w8 + 9202176);     //  8,388,608 B -> total 17,590,784 B

  k_merge <<<1440, 256, 0, stream>>>(wp, bp, wm, bm, wc, bc, wconv, Wpk, Bc, W2pk);
  k_fused <<<1024, 256, 0, stream>>>(x, ref, wcd, bcd, fusedt, xtb);
  k_all   <<<1024, 256, 0, stream>>>(Wpk, fusedt, Bc, xtb, W2pk, out);
}

// Round 2
// 260.951 us; speedup vs baseline: 1.0538x; 1.0538x over previous
//
#include <hip/hip_runtime.h>
#include <hip/hip_bf16.h>
#include <math.h>

typedef short s16x8 __attribute__((ext_vector_type(8)));
typedef float f32x4 __attribute__((ext_vector_type(4)));

__device__ inline ushort f2bf(float f) {
  unsigned u = __float_as_uint(f);
  u = (u + 0x7FFF + ((u >> 16) & 1)) >> 16;
  return (ushort)u;
}
__device__ inline float bf2f(ushort u) {
  return __uint_as_float(((unsigned)u) << 16);
}
// packed f32x2 -> bf16x2 RNE (bit-identical to f2bf pair)
__device__ inline unsigned pkbf(float a, float b) {
  __hip_bfloat162 h = __float22bfloat162_rn(make_float2(a, b));
  return *(unsigned*)&h;
}
// bf16 pair unpack from a dword: low half / high half (bit-identical to bf2f)
__device__ inline float bflo(unsigned u) { return __uint_as_float(u << 16); }
__device__ inline float bfhi(unsigned u) { return __uint_as_float(u & 0xffff0000u); }
// fast activations: v_exp_f32 + v_rcp_f32; saturate correctly at +/-inf.
__device__ inline float fast_tanh(float v) {
  float e = __builtin_amdgcn_exp2f(v * 2.8853900817779268f);   // exp(2v)
  return 1.f - 2.f * __builtin_amdgcn_rcpf(e + 1.f);
}
__device__ inline float fast_sigmoid(float v) {
  float e = __builtin_amdgcn_exp2f(v * -1.4426950408889634f);  // exp(-v)
  return __builtin_amdgcn_rcpf(1.f + e);
}

// ---- PERMUTED head-row space (640 rows):
//   g in [0,18): off | [18,27): mod | [27,64): pad | [64,640): col j=g-64=k*64+c
//     source col channel cc = c*9+k.
// ---- K0: pack weights into MFMA-fragment order in permuted row space ------------------
// Wpk[og 5][ks 18][ocq 2][mi 4][lane 64][e 8]; W2pk[ks 18][mi 4][lane 64][e 8].
__global__ __launch_bounds__(256) void k_merge(
    const float* __restrict__ wp, const float* __restrict__ bp,
    const float* __restrict__ wm, const float* __restrict__ bm,
    const float* __restrict__ wc, const float* __restrict__ bc,
    const float* __restrict__ wconv,
    ushort* __restrict__ Wpk, float* __restrict__ Bc, ushort* __restrict__ W2pk) {
  int i = blockIdx.x * 256 + threadIdx.x;
  if (i < 368640) {
    int e = i & 7, lane = (i >> 3) & 63, mi = (i >> 9) & 3, ocq = (i >> 11) & 1;
    int hi = i >> 12;                 // 0..89
    int ks = hi % 18, og = hi / 18;
    int g = og * 128 + ocq * 64 + mi * 16 + (lane & 15);
    int ci = ((ks & 1) << 5) + ((lane >> 4) << 3) + e;
    int kk = ks >> 1;
    int col = ci * 9 + kk;
    float v = 0.f;
    if (g < 18)       v = wp[g * 576 + col];
    else if (g < 27)  v = wm[(g - 18) * 576 + col];
    else if (g >= 64) {
      int j = g - 64;
      int cc = (j & 63) * 9 + (j >> 6);
      v = wc[cc * 576 + col];
    }
    Wpk[i] = f2bf(v);
  }
  if (i < 36864) {
    int e = i & 7, lane = (i >> 3) & 63, mi = (i >> 9) & 3, ks = i >> 11;  // 0..17
    int o = mi * 16 + (lane & 15);
    int p = (ks << 5) + ((lane >> 4) << 3) + e;
    int kk2 = p >> 6, c = p & 63;
    W2pk[i] = f2bf(wconv[o * 576 + c * 9 + kk2]);
  }
  if (i < 640) {
    float bv = 0.f;
    if (i < 18)       bv = bp[i];
    else if (i < 27)  bv = bm[i - 18];
    else if (i >= 64) {
      int j = i - 64;
      bv = bc[(j & 63) * 9 + (j >> 6)];
    }
    Bc[i] = bv;
  }
}

// ---- K1: fused = 1x1 conv -> fusedt[pix][64] bf16, PLUS xtb transpose (folded k_xt) ---
// 4 thr/px x 16 oc; x tile staged once in LDS and reused for both outputs.
__global__ __launch_bounds__(256) void k_fused(
    const float* __restrict__ x, const float* __restrict__ ref,
    const float* __restrict__ wcd, const float* __restrict__ bcd,
    ushort* __restrict__ fusedt, ushort* __restrict__ xtb) {
  __shared__ float sw[128 * 64];
  __shared__ float sx[64][65];
  __shared__ float sb[64];
  const int t = threadIdx.x;
  for (int i = t; i < 128 * 64; i += 256) {
    int ci = i >> 6, o = i & 63;
    sw[i] = wcd[o * 128 + ci];
  }
  if (t < 64) sb[t] = bcd[t];
  const int b = blockIdx.x >> 8, hw0 = (blockIdx.x & 255) << 6;
  for (int i = t; i < 4096; i += 256) {
    int c = i >> 6, hwi = i & 63;
    sx[c][hwi] = x[((size_t)((b << 6) + c) << 14) + hw0 + hwi];
  }
  __syncthreads();

  // xtb[b][hw][c] bf16 pixel-major (reads sx only; no hazard with GEMM reads below)
  for (int i = t * 2; i < 4096; i += 512) {
    int hwi = i >> 6, c = i & 63;    // c even
    unsigned pk = pkbf(sx[c][hwi], sx[c + 1][hwi]);
    *(unsigned*)(xtb + (((size_t)b << 14) + hw0 + hwi) * 64 + c) = pk;
  }

  const int pxi = t & 63, oq = t >> 6;      // wave-uniform oq -> LDS broadcast
  const int pix = blockIdx.x * 64 + pxi;
  const float* rb = ref + (((size_t)b << 6) << 14) + hw0 + pxi;

  float4 acc[4];
  #pragma unroll
  for (int q = 0; q < 4; q++)
    acc[q] = *(const float4*)&sb[oq * 16 + 4 * q];

  for (int ci = 0; ci < 64; ci++) {
    float v = sx[ci][pxi];
    const float4* wr = (const float4*)&sw[ci * 64 + oq * 16];
    #pragma unroll
    for (int q = 0; q < 4; q++) {
      float4 w4 = wr[q];
      acc[q].x += w4.x * v; acc[q].y += w4.y * v;
      acc[q].z += w4.z * v; acc[q].w += w4.w * v;
    }
  }
  for (int ci = 0; ci < 64; ci++) {
    float v = rb[(size_t)ci << 14];
    const float4* wr = (const float4*)&sw[(64 + ci) * 64 + oq * 16];
    #pragma unroll
    for (int q = 0; q < 4; q++) {
      float4 w4 = wr[q];
      acc[q].x += w4.x * v; acc[q].y += w4.y * v;
      acc[q].z += w4.z * v; acc[q].w += w4.w * v;
    }
  }
  uint4 o0, o1;
  o0.x = pkbf(acc[0].x, acc[0].y); o0.y = pkbf(acc[0].z, acc[0].w);
  o0.z = pkbf(acc[1].x, acc[1].y); o0.w = pkbf(acc[1].z, acc[1].w);
  o1.x = pkbf(acc[2].x, acc[2].y); o1.y = pkbf(acc[2].z, acc[2].w);
  o1.z = pkbf(acc[3].x, acc[3].y); o1.w = pkbf(acc[3].z, acc[3].w);
  ushort* fb = fusedt + ((size_t)pix << 6) + oq * 16;
  *(uint4*)fb       = o0;
  *(uint4*)(fb + 8) = o1;
}

// ---- K3: FULLY FUSED head-GEMM + sampler + final GEMM, 64-px tiles --------------------
// grid 1024; block 256 = 4 waves; LDS 40,448B -> 4 blocks/CU (the round-1 regression was
// the colT double-buffer pushing LDS past the 4-block boundary: occupancy 36->23%).
// Fix: sampler FUSED into the col-GEMM epilogue. Each epilogue thread gathers the
// bilinear corners for its own (px, ch) pairs and writes (tanh+pos)*mod to colT ONCE.
// -> single colT buffer, 2 barriers/k, no colT read-modify-write, no sampler phase.
// Round-1 keeps: invariant sF/colT offsets in regs, readfirstlane weight bases,
// packed bf16 converts, rebalanced off/mod GEMM.
__global__ __launch_bounds__(256, 4) void k_all(
    const ushort* __restrict__ Wpk, const ushort* __restrict__ fusedt,
    const float* __restrict__ Bc, const ushort* __restrict__ xtb,
    const ushort* __restrict__ W2pk, float* __restrict__ out) {
  __shared__ __align__(16) ushort sF[3 * 66 * 64];    // 25,344 B
  __shared__ __align__(16) ushort colT[64 * 64];      //  8,192 B
  __shared__ float homT[64 * 27];                     //  6,912 B -> 40,448 B total
  const int t = threadIdx.x;
  const int lane = t & 63, wv = t >> 6;
  const int rowid = blockIdx.x;           // b*256 + h*2 + half
  const int b = rowid >> 8;
  const int rem = rowid & 255;
  const int h = rem >> 1, hf = rem & 1;
  const int w0 = hf << 6;
  const int hw0 = (h << 7) + w0;

  // stage fused rows h-1..h+1, w1 in [0,66) covering gw in [w0-1, w0+64]
  for (int idx = t; idx < 1584; idx += 256) {   // 198 pixels x 8 ci-chunks
    int p = idx >> 3, j = idx & 7;
    int row = p / 66, w1 = p - row * 66;
    int gh = h + row - 1, gw = w0 + w1 - 1;
    uint4 v = make_uint4(0u, 0u, 0u, 0u);
    if (gh >= 0 && gh < 128 && (unsigned)gw < 128u)
      v = *(const uint4*)(fusedt + ((size_t)((b << 14) + (gh << 7) + gw) << 6) + j * 8);
    int slot = (j + w1) & 7;
    *(uint4*)(sF + (p << 6) + slot * 8) = v;
  }

  const int pxq = wv & 1, rowq = wv >> 1;
  const int nif = lane & 15, kb = lane >> 4, quad = lane >> 4;
  const int wlaneoff = lane << 3;                          // element offset in weight row
  const int rfq = __builtin_amdgcn_readfirstlane(rowq);    // wave-uniform -> SGPR
  const int rowel9  = rfq << 9;                            // off/mod af offset (mi=rowq)
  const int rowel10 = rfq << 10;                           // col/final af base

  // invariant sF read offsets (ushort elements): reused by all 10 head GEMMs
  int sfo[18][2];
  #pragma unroll
  for (int ks = 0; ks < 18; ks++) {
    const int kk = ks >> 1, half = ks & 1;
    const int dr = kk / 3, dc = kk - dr * 3;
    const int gci = half * 4 + kb;
    #pragma unroll
    for (int ni = 0; ni < 2; ni++) {
      const int r = (pxq << 5) + ni * 16 + nif;
      const int w1 = r + dc;
      sfo[ks][ni] = ((dr * 66 + w1) << 6) + (((gci + w1) & 7) << 3);
    }
  }
  // invariant colT read offsets for the final GEMM
  int cto[2][2];
  #pragma unroll
  for (int khalf = 0; khalf < 2; khalf++) {
    const int g0 = (khalf << 2) + kb;
    #pragma unroll
    for (int ni = 0; ni < 2; ni++) {
      const int r = (pxq << 5) + ni * 16 + nif;
      cto[khalf][ni] = (r << 6) + (((g0 + r) & 7) << 3);
    }
  }

  __syncthreads();

  // ---- off/mod GEMM: wave (rowq,pxq) computes rows rowq*16..+16 of its 32 px ----
  {
    f32x4 acc[2];
    acc[0] = (f32x4){0.f, 0.f, 0.f, 0.f};
    acc[1] = (f32x4){0.f, 0.f, 0.f, 0.f};
    #pragma unroll
    for (int ks = 0; ks < 18; ks++) {
      s16x8 af = *(const s16x8*)(Wpk + (ks << 12) + rowel9 + wlaneoff);
      s16x8 b0 = *(const s16x8*)(sF + sfo[ks][0]);
      s16x8 b1 = *(const s16x8*)(sF + sfo[ks][1]);
      acc[0] = __builtin_amdgcn_mfma_f32_16x16x32_bf16(af, b0, acc[0], 0, 0, 0);
      acc[1] = __builtin_amdgcn_mfma_f32_16x16x32_bf16(af, b1, acc[1], 0, 0, 0);
    }
    const float4 b4 = *(const float4*)(Bc + (rowq << 4) + (quad << 2));
    const float bb[4] = {b4.x, b4.y, b4.z, b4.w};
    #pragma unroll
    for (int ni = 0; ni < 2; ni++) {
      const int px = (pxq << 5) + ni * 16 + nif;
      #pragma unroll
      for (int r = 0; r < 4; r++) {
        const int g = (rowq << 4) + (quad << 2) + r;
        float v = acc[ni][r] + bb[r];
        if (g < 18)       homT[px * 27 + g] = v;
        else if (g < 27)  homT[px * 27 + g] = fast_sigmoid(v);
      }
    }
  }

  const ushort* xb0 = xtb + ((size_t)b << 20);

  f32x4 aco[2][2];
  #pragma unroll
  for (int mi = 0; mi < 2; mi++)
    #pragma unroll
    for (int ni = 0; ni < 2; ni++) aco[mi][ni] = (f32x4){0.f, 0.f, 0.f, 0.f};

  #pragma unroll 1
  for (int k = 0; k < 9; k++) {
    // ---- col GEMM for this k: permuted rows 64+k*64 .. 128+k*64 ----
    const int q = 1 + k, og = q >> 1, ocq = q & 1;
    const ushort* wb = Wpk + ((size_t)(((og * 36) + ocq) << 11)) + rowel10 + wlaneoff;
    f32x4 acc[2][2];
    #pragma unroll
    for (int mi = 0; mi < 2; mi++)
      #pragma unroll
      for (int ni = 0; ni < 2; ni++) acc[mi][ni] = (f32x4){0.f, 0.f, 0.f, 0.f};
    #pragma unroll
    for (int ks = 0; ks < 18; ks++) {
      const ushort* wp8 = wb + (ks << 12);
      s16x8 af0 = *(const s16x8*)(wp8);
      s16x8 af1 = *(const s16x8*)(wp8 + 512);
      s16x8 b0 = *(const s16x8*)(sF + sfo[ks][0]);
      s16x8 b1 = *(const s16x8*)(sF + sfo[ks][1]);
      acc[0][0] = __builtin_amdgcn_mfma_f32_16x16x32_bf16(af0, b0, acc[0][0], 0, 0, 0);
      acc[0][1] = __builtin_amdgcn_mfma_f32_16x16x32_bf16(af0, b1, acc[0][1], 0, 0, 0);
      acc[1][0] = __builtin_amdgcn_mfma_f32_16x16x32_bf16(af1, b0, acc[1][0], 0, 0, 0);
      acc[1][1] = __builtin_amdgcn_mfma_f32_16x16x32_bf16(af1, b1, acc[1][1], 0, 0, 0);
    }

    __syncthreads();   // prior k's final-MFMA colT reads done; homT visible at k=0

    // ---- fused epilogue: tanh + bilinear gather + modulate -> colT (single write) ----
    {
      const int kdr = k / 3, kdc = k - kdr * 3;
      #pragma unroll
      for (int ni = 0; ni < 2; ni++) {
        const int px = (pxq << 5) + ni * 16 + nif;
        const int hb = px * 27;
        float ox = homT[hb + k];
        float oy = homT[hb + 9 + k];
        float mk = homT[hb + 18 + k];
        float px_ = (float)(h + kdr) + ox;
        float py_ = (float)(w0 + px + kdc) + oy;
        float fx = floorf(px_), fy = floorf(py_);
        float qltx = fminf(fmaxf(fx, 0.f), 129.f);
        float qlty = fminf(fmaxf(fy, 0.f), 129.f);
        float qrbx = fminf(fmaxf(fx + 1.f, 0.f), 129.f);
        float qrby = fminf(fmaxf(fy + 1.f, 0.f), 129.f);
        float sx = fminf(fmaxf(px_, 0.f), 129.f);
        float sy = fminf(fmaxf(py_, 0.f), 129.f);
        float ax = 1.f + qltx - sx, bx = 1.f - qrbx + sx;
        float ay = 1.f + qlty - sy, by = 1.f - qrby + sy;
        int iltx = (int)qltx, ilty = (int)qlty, irbx = (int)qrbx, irby = (int)qrby;
        bool vltx = (iltx >= 1) && (iltx <= 128);
        bool vlty = (ilty >= 1) && (ilty <= 128);
        bool vrbx = (irbx >= 1) && (irbx <= 128);
        bool vrby = (irby >= 1) && (irby <= 128);
        float wl[4];
        int   ofs[4];
        wl[0] = (vltx && vlty) ? ax * ay : 0.f;
        wl[1] = (vrbx && vrby) ? bx * by : 0.f;
        wl[2] = (vltx && vrby) ? ax * by : 0.f;
        wl[3] = (vrbx && vlty) ? bx * ay : 0.f;
        ofs[0] = (vltx && vlty) ? ((iltx - 1) << 7) + (ilty - 1) : 0;
        ofs[1] = (vrbx && vrby) ? ((irbx - 1) << 7) + (irby - 1) : 0;
        ofs[2] = (vltx && vrby) ? ((iltx - 1) << 7) + (irby - 1) : 0;
        ofs[3] = (vrbx && vlty) ? ((irbx - 1) << 7) + (ilty - 1) : 0;

        #pragma unroll
        for (int mi = 0; mi < 2; mi++) {
          const int c = (rowq << 5) + mi * 16 + (quad << 2);
          const float4 b4 = *(const float4*)(Bc + 64 + (k << 6) + c);
          float pos0 = 0.f, pos1 = 0.f, pos2 = 0.f, pos3 = 0.f;
          #pragma unroll
          for (int corner = 0; corner < 4; corner++) {
            const ushort* p = xb0 + ((size_t)ofs[corner] << 6) + c;
            uint2 A = *(const uint2*)p;
            float wgt = wl[corner];
            pos0 += wgt * bflo(A.x); pos1 += wgt * bfhi(A.x);
            pos2 += wgt * bflo(A.y); pos3 += wgt * bfhi(A.y);
          }
          float v0 = (fast_tanh(acc[mi][ni][0] + b4.x) + pos0) * mk;
          float v1 = (fast_tanh(acc[mi][ni][1] + b4.y) + pos1) * mk;
          float v2 = (fast_tanh(acc[mi][ni][2] + b4.z) + pos2) * mk;
          float v3 = (fast_tanh(acc[mi][ni][3] + b4.w) + pos3) * mk;
          uint2 pk2;
          pk2.x = pkbf(v0, v1);
          pk2.y = pkbf(v2, v3);
          const int slot = ((c >> 3) + px) & 7;
          *(uint2*)(colT + (px << 6) + slot * 8 + (c & 7)) = pk2;
        }
      }
    }
    __syncthreads();   // colT ready for final MFMA

    // ---- final-GEMM MFMA: 2 ks-steps over this k-tile ----
    #pragma unroll
    for (int khalf = 0; khalf < 2; khalf++) {
      const int ks2 = (k << 1) + khalf;
      const ushort* w2 = W2pk + (ks2 << 11) + rowel10 + wlaneoff;
      s16x8 af0 = *(const s16x8*)(w2);
      s16x8 af1 = *(const s16x8*)(w2 + 512);
      s16x8 b0 = *(const s16x8*)(colT + cto[khalf][0]);
      s16x8 b1 = *(const s16x8*)(colT + cto[khalf][1]);
      aco[0][0] = __builtin_amdgcn_mfma_f32_16x16x32_bf16(af0, b0, aco[0][0], 0, 0, 0);
      aco[0][1] = __builtin_amdgcn_mfma_f32_16x16x32_bf16(af0, b1, aco[0][1], 0, 0, 0);
      aco[1][0] = __builtin_amdgcn_mfma_f32_16x16x32_bf16(af1, b0, aco[1][0], 0, 0, 0);
      aco[1][1] = __builtin_amdgcn_mfma_f32_16x16x32_bf16(af1, b1, aco[1][1], 0, 0, 0);
    }
  }

  // ---- store out ----
  #pragma unroll
  for (int mi = 0; mi < 2; mi++) {
    #pragma unroll
    for (int ni = 0; ni < 2; ni++) {
      int hwp = hw0 + (pxq << 5) + ni * 16 + nif;
      #pragma unroll
      for (int r = 0; r < 4; r++) {
        int o = (rowq << 5) + mi * 16 + (quad << 2) + r;
        out[(((size_t)b * 64 + o) << 14) + hwp] = aco[mi][ni][r];
      }
    }
  }
}

extern "C" void kernel_launch(void* const* d_in, const int* in_sizes, int n_in,
                              void* d_out, int out_size, void* d_ws, size_t ws_size,
                              hipStream_t stream) {
  const float* x     = (const float*)d_in[0];
  const float* ref   = (const float*)d_in[1];
  const float* wcd   = (const float*)d_in[2];
  const float* bcd   = (const float*)d_in[3];
  const float* wp    = (const float*)d_in[4];
  const float* bp    = (const float*)d_in[5];
  const float* wm    = (const float*)d_in[6];
  const float* bm    = (const float*)d_in[7];
  const float* wc    = (const float*)d_in[8];
  const float* bc    = (const float*)d_in[9];
  const float* wconv = (const float*)d_in[10];
  float* out = (float*)d_out;

  char* w8 = (char*)d_ws;
  ushort* Wpk     = (ushort*)(w8 + 0);           //    737,280 B
  float*  Bc      = (float*)(w8 + 737280);       //      2,560 B
  ushort* W2pk    = (ushort*)(w8 + 739840);      //     73,728 B
  ushort* fusedt  = (ushort*)(w8 + 813568);      //  8,388,608 B (pixel-major)
  ushort* xtb     = (ushort*)(w8 + 9202176);     //  8,388,608 B -> total 17,590,784 B

  k_merge <<<1440, 256, 0, stream>>>(wp, bp, wm, bm, wc, bc, wconv, Wpk, Bc, W2pk);
  k_fused <<<1024, 256, 0, stream>>>(x, ref, wcd, bcd, fusedt, xtb);
  k_all   <<<1024, 256, 0, stream>>>(Wpk, fusedt, Bc, xtb, W2pk, out);
}

// Round 3
// 259.722 us; speedup vs baseline: 1.0588x; 1.0047x over previous
//
#include <hip/hip_runtime.h>
#include <hip/hip_bf16.h>
#include <math.h>

typedef short s16x8 __attribute__((ext_vector_type(8)));
typedef float f32x4 __attribute__((ext_vector_type(4)));

__device__ inline ushort f2bf(float f) {
  unsigned u = __float_as_uint(f);
  u = (u + 0x7FFF + ((u >> 16) & 1)) >> 16;
  return (ushort)u;
}
__device__ inline float bf2f(ushort u) {
  return __uint_as_float(((unsigned)u) << 16);
}
// packed f32x2 -> bf16x2 RNE (bit-identical to f2bf pair)
__device__ inline unsigned pkbf(float a, float b) {
  __hip_bfloat162 h = __float22bfloat162_rn(make_float2(a, b));
  return *(unsigned*)&h;
}
// bf16 pair unpack from a dword: low half / high half (bit-identical to bf2f)
__device__ inline float bflo(unsigned u) { return __uint_as_float(u << 16); }
__device__ inline float bfhi(unsigned u) { return __uint_as_float(u & 0xffff0000u); }
// fast activations: v_exp_f32 + v_rcp_f32; saturate correctly at +/-inf.
__device__ inline float fast_tanh(float v) {
  float e = __builtin_amdgcn_exp2f(v * 2.8853900817779268f);   // exp(2v)
  return 1.f - 2.f * __builtin_amdgcn_rcpf(e + 1.f);
}
__device__ inline float fast_sigmoid(float v) {
  float e = __builtin_amdgcn_exp2f(v * -1.4426950408889634f);  // exp(-v)
  return __builtin_amdgcn_rcpf(1.f + e);
}

// LDS-only barrier: orders ds ops across waves WITHOUT draining vmcnt (so prefetched
// global loads stay in flight across phase boundaries). __syncthreads() would emit a
// workgroup release fence = s_waitcnt vmcnt(0) too, killing the gather pipeline.
#define LDS_BARRIER()                                          \
  do {                                                         \
    asm volatile("s_waitcnt lgkmcnt(0)" ::: "memory");         \
    __builtin_amdgcn_s_barrier();                              \
  } while (0)

// ---- PERMUTED head-row space (640 rows):
//   g in [0,18): off | [18,27): mod | [27,64): pad | [64,640): col j=g-64=k*64+c
//     source col channel cc = c*9+k.
// ---- K0: pack weights into MFMA-fragment order in permuted row space ------------------
// Wpk[og 5][ks 18][ocq 2][mi 4][lane 64][e 8]; W2pk[ks 18][mi 4][lane 64][e 8].
__global__ __launch_bounds__(256) void k_merge(
    const float* __restrict__ wp, const float* __restrict__ bp,
    const float* __restrict__ wm, const float* __restrict__ bm,
    const float* __restrict__ wc, const float* __restrict__ bc,
    const float* __restrict__ wconv,
    ushort* __restrict__ Wpk, float* __restrict__ Bc, ushort* __restrict__ W2pk) {
  int i = blockIdx.x * 256 + threadIdx.x;
  if (i < 368640) {
    int e = i & 7, lane = (i >> 3) & 63, mi = (i >> 9) & 3, ocq = (i >> 11) & 1;
    int hi = i >> 12;                 // 0..89
    int ks = hi % 18, og = hi / 18;
    int g = og * 128 + ocq * 64 + mi * 16 + (lane & 15);
    int ci = ((ks & 1) << 5) + ((lane >> 4) << 3) + e;
    int kk = ks >> 1;
    int col = ci * 9 + kk;
    float v = 0.f;
    if (g < 18)       v = wp[g * 576 + col];
    else if (g < 27)  v = wm[(g - 18) * 576 + col];
    else if (g >= 64) {
      int j = g - 64;
      int cc = (j & 63) * 9 + (j >> 6);
      v = wc[cc * 576 + col];
    }
    Wpk[i] = f2bf(v);
  }
  if (i < 36864) {
    int e = i & 7, lane = (i >> 3) & 63, mi = (i >> 9) & 3, ks = i >> 11;  // 0..17
    int o = mi * 16 + (lane & 15);
    int p = (ks << 5) + ((lane >> 4) << 3) + e;
    int kk2 = p >> 6, c = p & 63;
    W2pk[i] = f2bf(wconv[o * 576 + c * 9 + kk2]);
  }
  if (i < 640) {
    float bv = 0.f;
    if (i < 18)       bv = bp[i];
    else if (i < 27)  bv = bm[i - 18];
    else if (i >= 64) {
      int j = i - 64;
      bv = bc[(j & 63) * 9 + (j >> 6)];
    }
    Bc[i] = bv;
  }
}

// ---- K1: fused = 1x1 conv -> fusedt[pix][64] bf16, PLUS xtb transpose (folded k_xt) ---
// 4 thr/px x 16 oc; x tile staged once in LDS and reused for both outputs.
__global__ __launch_bounds__(256) void k_fused(
    const float* __restrict__ x, const float* __restrict__ ref,
    const float* __restrict__ wcd, const float* __restrict__ bcd,
    ushort* __restrict__ fusedt, ushort* __restrict__ xtb) {
  __shared__ float sw[128 * 64];
  __shared__ float sx[64][65];
  __shared__ float sb[64];
  const int t = threadIdx.x;
  for (int i = t; i < 128 * 64; i += 256) {
    int ci = i >> 6, o = i & 63;
    sw[i] = wcd[o * 128 + ci];
  }
  if (t < 64) sb[t] = bcd[t];
  const int b = blockIdx.x >> 8, hw0 = (blockIdx.x & 255) << 6;
  for (int i = t; i < 4096; i += 256) {
    int c = i >> 6, hwi = i & 63;
    sx[c][hwi] = x[((size_t)((b << 6) + c) << 14) + hw0 + hwi];
  }
  __syncthreads();

  // xtb[b][hw][c] bf16 pixel-major (reads sx only; no hazard with GEMM reads below)
  for (int i = t * 2; i < 4096; i += 512) {
    int hwi = i >> 6, c = i & 63;    // c even
    unsigned pk = pkbf(sx[c][hwi], sx[c + 1][hwi]);
    *(unsigned*)(xtb + (((size_t)b << 14) + hw0 + hwi) * 64 + c) = pk;
  }

  const int pxi = t & 63, oq = t >> 6;      // wave-uniform oq -> LDS broadcast
  const int pix = blockIdx.x * 64 + pxi;
  const float* rb = ref + (((size_t)b << 6) << 14) + hw0 + pxi;

  float4 acc[4];
  #pragma unroll
  for (int q = 0; q < 4; q++)
    acc[q] = *(const float4*)&sb[oq * 16 + 4 * q];

  for (int ci = 0; ci < 64; ci++) {
    float v = sx[ci][pxi];
    const float4* wr = (const float4*)&sw[ci * 64 + oq * 16];
    #pragma unroll
    for (int q = 0; q < 4; q++) {
      float4 w4 = wr[q];
      acc[q].x += w4.x * v; acc[q].y += w4.y * v;
      acc[q].z += w4.z * v; acc[q].w += w4.w * v;
    }
  }
  for (int ci = 0; ci < 64; ci++) {
    float v = rb[(size_t)ci << 14];
    const float4* wr = (const float4*)&sw[(64 + ci) * 64 + oq * 16];
    #pragma unroll
    for (int q = 0; q < 4; q++) {
      float4 w4 = wr[q];
      acc[q].x += w4.x * v; acc[q].y += w4.y * v;
      acc[q].z += w4.z * v; acc[q].w += w4.w * v;
    }
  }
  uint4 o0, o1;
  o0.x = pkbf(acc[0].x, acc[0].y); o0.y = pkbf(acc[0].z, acc[0].w);
  o0.z = pkbf(acc[1].x, acc[1].y); o0.w = pkbf(acc[1].z, acc[1].w);
  o1.x = pkbf(acc[2].x, acc[2].y); o1.y = pkbf(acc[2].z, acc[2].w);
  o1.z = pkbf(acc[3].x, acc[3].y); o1.w = pkbf(acc[3].z, acc[3].w);
  ushort* fb = fusedt + ((size_t)pix << 6) + oq * 16;
  *(uint4*)fb       = o0;
  *(uint4*)(fb + 8) = o1;
}

// ---- K3: FULLY FUSED head-GEMM + sampler + final GEMM, 64-px tiles --------------------
// grid 1024; block 256 = 4 waves; LDS 40,448B -> 4 blocks/CU.
// Round-3: software-pipelined gathers. All sampling inputs (homT) exist before the
// k-loop, so corner loads for iteration k+1 are ISSUED during epilogue(k) and consumed
// in epilogue(k+1) (~500+ cycles of col-GEMM MFMA to hide under). W2pk fragments for
// final-MFMA(k) prefetched during epilogue(k). In-loop barriers are lgkmcnt-only
// (LDS_BARRIER) so prefetched global loads stay in flight across phases.
__global__ __launch_bounds__(256, 4) void k_all(
    const ushort* __restrict__ Wpk, const ushort* __restrict__ fusedt,
    const float* __restrict__ Bc, const ushort* __restrict__ xtb,
    const ushort* __restrict__ W2pk, float* __restrict__ out) {
  __shared__ __align__(16) ushort sF[3 * 66 * 64];    // 25,344 B
  __shared__ __align__(16) ushort colT[64 * 64];      //  8,192 B
  __shared__ float homT[64 * 27];                     //  6,912 B -> 40,448 B total
  const int t = threadIdx.x;
  const int lane = t & 63, wv = t >> 6;
  const int rowid = blockIdx.x;           // b*256 + h*2 + half
  const int b = rowid >> 8;
  const int rem = rowid & 255;
  const int h = rem >> 1, hf = rem & 1;
  const int w0 = hf << 6;
  const int hw0 = (h << 7) + w0;

  // stage fused rows h-1..h+1, w1 in [0,66) covering gw in [w0-1, w0+64]
  for (int idx = t; idx < 1584; idx += 256) {   // 198 pixels x 8 ci-chunks
    int p = idx >> 3, j = idx & 7;
    int row = p / 66, w1 = p - row * 66;
    int gh = h + row - 1, gw = w0 + w1 - 1;
    uint4 v = make_uint4(0u, 0u, 0u, 0u);
    if (gh >= 0 && gh < 128 && (unsigned)gw < 128u)
      v = *(const uint4*)(fusedt + ((size_t)((b << 14) + (gh << 7) + gw) << 6) + j * 8);
    int slot = (j + w1) & 7;
    *(uint4*)(sF + (p << 6) + slot * 8) = v;
  }

  const int pxq = wv & 1, rowq = wv >> 1;
  const int nif = lane & 15, kb = lane >> 4, quad = lane >> 4;
  const int wlaneoff = lane << 3;                          // element offset in weight row
  const int rfq = __builtin_amdgcn_readfirstlane(rowq);    // wave-uniform -> SGPR
  const int rowel9  = rfq << 9;                            // off/mod af offset (mi=rowq)
  const int rowel10 = rfq << 10;                           // col/final af base
  const int cbase = (rowq << 5) + (quad << 2);             // this thread's channel base

  // invariant sF read offsets (ushort elements): reused by all 10 head GEMMs
  int sfo[18][2];
  #pragma unroll
  for (int ks = 0; ks < 18; ks++) {
    const int kk = ks >> 1, half = ks & 1;
    const int dr = kk / 3, dc = kk - dr * 3;
    const int gci = half * 4 + kb;
    #pragma unroll
    for (int ni = 0; ni < 2; ni++) {
      const int r = (pxq << 5) + ni * 16 + nif;
      const int w1 = r + dc;
      sfo[ks][ni] = ((dr * 66 + w1) << 6) + (((gci + w1) & 7) << 3);
    }
  }
  // invariant colT read offsets for the final GEMM
  int cto[2][2];
  #pragma unroll
  for (int khalf = 0; khalf < 2; khalf++) {
    const int g0 = (khalf << 2) + kb;
    #pragma unroll
    for (int ni = 0; ni < 2; ni++) {
      const int r = (pxq << 5) + ni * 16 + nif;
      cto[khalf][ni] = (r << 6) + (((g0 + r) & 7) << 3);
    }
  }

  __syncthreads();

  // ---- off/mod GEMM: wave (rowq,pxq) computes rows rowq*16..+16 of its 32 px ----
  {
    f32x4 acc[2];
    acc[0] = (f32x4){0.f, 0.f, 0.f, 0.f};
    acc[1] = (f32x4){0.f, 0.f, 0.f, 0.f};
    #pragma unroll
    for (int ks = 0; ks < 18; ks++) {
      s16x8 af = *(const s16x8*)(Wpk + (ks << 12) + rowel9 + wlaneoff);
      s16x8 b0 = *(const s16x8*)(sF + sfo[ks][0]);
      s16x8 b1 = *(const s16x8*)(sF + sfo[ks][1]);
      acc[0] = __builtin_amdgcn_mfma_f32_16x16x32_bf16(af, b0, acc[0], 0, 0, 0);
      acc[1] = __builtin_amdgcn_mfma_f32_16x16x32_bf16(af, b1, acc[1], 0, 0, 0);
    }
    const float4 b4 = *(const float4*)(Bc + (rowq << 4) + (quad << 2));
    const float bb[4] = {b4.x, b4.y, b4.z, b4.w};
    #pragma unroll
    for (int ni = 0; ni < 2; ni++) {
      const int px = (pxq << 5) + ni * 16 + nif;
      #pragma unroll
      for (int r = 0; r < 4; r++) {
        const int g = (rowq << 4) + (quad << 2) + r;
        float v = acc[ni][r] + bb[r];
        if (g < 18)       homT[px * 27 + g] = v;
        else if (g < 27)  homT[px * 27 + g] = fast_sigmoid(v);
      }
    }
  }

  __syncthreads();   // homT (written by both rowq waves) visible to everyone

  const ushort* xb0 = xtb + ((size_t)b << 20);

  // ---- gather-prefetch state (consumed one iteration later) ----
  float mkv[2];
  float wlv[2][4];
  uint2 gpre[2][2][4];   // [ni][mi][corner]

  auto prefetch_k = [&](int kk) {
    const int kdr = kk / 3, kdc = kk - kdr * 3;
    #pragma unroll
    for (int ni = 0; ni < 2; ni++) {
      const int px = (pxq << 5) + ni * 16 + nif;
      const int hb = px * 27;
      float ox = homT[hb + kk];
      float oy = homT[hb + 9 + kk];
      mkv[ni] = homT[hb + 18 + kk];
      float px_ = (float)(h + kdr) + ox;
      float py_ = (float)(w0 + px + kdc) + oy;
      float fx = floorf(px_), fy = floorf(py_);
      float qltx = fminf(fmaxf(fx, 0.f), 129.f);
      float qlty = fminf(fmaxf(fy, 0.f), 129.f);
      float qrbx = fminf(fmaxf(fx + 1.f, 0.f), 129.f);
      float qrby = fminf(fmaxf(fy + 1.f, 0.f), 129.f);
      float sx = fminf(fmaxf(px_, 0.f), 129.f);
      float sy = fminf(fmaxf(py_, 0.f), 129.f);
      float ax = 1.f + qltx - sx, bx = 1.f - qrbx + sx;
      float ay = 1.f + qlty - sy, by = 1.f - qrby + sy;
      int iltx = (int)qltx, ilty = (int)qlty, irbx = (int)qrbx, irby = (int)qrby;
      bool vltx = (iltx >= 1) && (iltx <= 128);
      bool vlty = (ilty >= 1) && (ilty <= 128);
      bool vrbx = (irbx >= 1) && (irbx <= 128);
      bool vrby = (irby >= 1) && (irby <= 128);
      float wl[4];
      int   ofs[4];
      wl[0] = (vltx && vlty) ? ax * ay : 0.f;
      wl[1] = (vrbx && vrby) ? bx * by : 0.f;
      wl[2] = (vltx && vrby) ? ax * by : 0.f;
      wl[3] = (vrbx && vlty) ? bx * ay : 0.f;
      ofs[0] = (vltx && vlty) ? ((iltx - 1) << 7) + (ilty - 1) : 0;
      ofs[1] = (vrbx && vrby) ? ((irbx - 1) << 7) + (irby - 1) : 0;
      ofs[2] = (vltx && vrby) ? ((iltx - 1) << 7) + (irby - 1) : 0;
      ofs[3] = (vrbx && vlty) ? ((irbx - 1) << 7) + (ilty - 1) : 0;
      #pragma unroll
      for (int corner = 0; corner < 4; corner++) {
        wlv[ni][corner] = wl[corner];
        const ushort* p = xb0 + ((size_t)ofs[corner] << 6) + cbase;
        gpre[ni][0][corner] = *(const uint2*)p;        // mi=0: channels cbase..+3
        gpre[ni][1][corner] = *(const uint2*)(p + 16); // mi=1: channels cbase+16..+19
      }
    }
  };

  prefetch_k(0);   // loads in flight across col-GEMM(0)

  f32x4 aco[2][2];
  #pragma unroll
  for (int mi = 0; mi < 2; mi++)
    #pragma unroll
    for (int ni = 0; ni < 2; ni++) aco[mi][ni] = (f32x4){0.f, 0.f, 0.f, 0.f};

  s16x8 w2pre[2][2];   // [khalf][mi] final-GEMM fragments, prefetched per k

  #pragma unroll 1
  for (int k = 0; k < 9; k++) {
    // ---- col GEMM for this k: permuted rows 64+k*64 .. 128+k*64 ----
    const int q = 1 + k, og = q >> 1, ocq = q & 1;
    const ushort* wb = Wpk + ((size_t)(((og * 36) + ocq) << 11)) + rowel10 + wlaneoff;
    f32x4 acc[2][2];
    #pragma unroll
    for (int mi = 0; mi < 2; mi++)
      #pragma unroll
      for (int ni = 0; ni < 2; ni++) acc[mi][ni] = (f32x4){0.f, 0.f, 0.f, 0.f};
    __builtin_amdgcn_s_setprio(1);
    #pragma unroll
    for (int ks = 0; ks < 18; ks++) {
      const ushort* wp8 = wb + (ks << 12);
      s16x8 af0 = *(const s16x8*)(wp8);
      s16x8 af1 = *(const s16x8*)(wp8 + 512);
      s16x8 b0 = *(const s16x8*)(sF + sfo[ks][0]);
      s16x8 b1 = *(const s16x8*)(sF + sfo[ks][1]);
      acc[0][0] = __builtin_amdgcn_mfma_f32_16x16x32_bf16(af0, b0, acc[0][0], 0, 0, 0);
      acc[0][1] = __builtin_amdgcn_mfma_f32_16x16x32_bf16(af0, b1, acc[0][1], 0, 0, 0);
      acc[1][0] = __builtin_amdgcn_mfma_f32_16x16x32_bf16(af1, b0, acc[1][0], 0, 0, 0);
      acc[1][1] = __builtin_amdgcn_mfma_f32_16x16x32_bf16(af1, b1, acc[1][1], 0, 0, 0);
    }
    __builtin_amdgcn_s_setprio(0);

    LDS_BARRIER();   // B1: prior final-MFMA colT ds_reads done before overwrite (WAR)

    // ---- epilogue: tanh + prefetched bilinear gather + modulate -> colT ----
    {
      #pragma unroll
      for (int ni = 0; ni < 2; ni++) {
        const int px = (pxq << 5) + ni * 16 + nif;
        const float mk = mkv[ni];
        #pragma unroll
        for (int mi = 0; mi < 2; mi++) {
          const int c = cbase + mi * 16;
          const float4 b4 = *(const float4*)(Bc + 64 + (k << 6) + c);
          float pos0 = 0.f, pos1 = 0.f, pos2 = 0.f, pos3 = 0.f;
          #pragma unroll
          for (int corner = 0; corner < 4; corner++) {
            uint2 A = gpre[ni][mi][corner];
            float wgt = wlv[ni][corner];
            pos0 += wgt * bflo(A.x); pos1 += wgt * bfhi(A.x);
            pos2 += wgt * bflo(A.y); pos3 += wgt * bfhi(A.y);
          }
          float v0 = (fast_tanh(acc[mi][ni][0] + b4.x) + pos0) * mk;
          float v1 = (fast_tanh(acc[mi][ni][1] + b4.y) + pos1) * mk;
          float v2 = (fast_tanh(acc[mi][ni][2] + b4.z) + pos2) * mk;
          float v3 = (fast_tanh(acc[mi][ni][3] + b4.w) + pos3) * mk;
          uint2 pk2;
          pk2.x = pkbf(v0, v1);
          pk2.y = pkbf(v2, v3);
          const int slot = ((c >> 3) + px) & 7;
          *(uint2*)(colT + (px << 6) + slot * 8 + (c & 7)) = pk2;
        }
      }
    }

    // prefetch final-GEMM weight fragments for THIS k (used right after B2)
    #pragma unroll
    for (int khalf = 0; khalf < 2; khalf++) {
      const ushort* w2 = W2pk + (((k << 1) + khalf) << 11) + rowel10 + wlaneoff;
      w2pre[khalf][0] = *(const s16x8*)(w2);
      w2pre[khalf][1] = *(const s16x8*)(w2 + 512);
    }
    // prefetch gathers for k+1 (complete during final-MFMA(k) + col-GEMM(k+1))
    if (k < 8) prefetch_k(k + 1);

    LDS_BARRIER();   // B2: colT writes visible to final MFMA (RAW); vmcnt NOT drained

    // ---- final-GEMM MFMA: 2 ks-steps over this k-tile ----
    __builtin_amdgcn_s_setprio(1);
    #pragma unroll
    for (int khalf = 0; khalf < 2; khalf++) {
      s16x8 b0 = *(const s16x8*)(colT + cto[khalf][0]);
      s16x8 b1 = *(const s16x8*)(colT + cto[khalf][1]);
      aco[0][0] = __builtin_amdgcn_mfma_f32_16x16x32_bf16(w2pre[khalf][0], b0, aco[0][0], 0, 0, 0);
      aco[0][1] = __builtin_amdgcn_mfma_f32_16x16x32_bf16(w2pre[khalf][0], b1, aco[0][1], 0, 0, 0);
      aco[1][0] = __builtin_amdgcn_mfma_f32_16x16x32_bf16(w2pre[khalf][1], b0, aco[1][0], 0, 0, 0);
      aco[1][1] = __builtin_amdgcn_mfma_f32_16x16x32_bf16(w2pre[khalf][1], b1, aco[1][1], 0, 0, 0);
    }
    __builtin_amdgcn_s_setprio(0);
  }

  // ---- store out ----
  #pragma unroll
  for (int mi = 0; mi < 2; mi++) {
    #pragma unroll
    for (int ni = 0; ni < 2; ni++) {
      int hwp = hw0 + (pxq << 5) + ni * 16 + nif;
      #pragma unroll
      for (int r = 0; r < 4; r++) {
        int o = (rowq << 5) + mi * 16 + (quad << 2) + r;
        out[(((size_t)b * 64 + o) << 14) + hwp] = aco[mi][ni][r];
      }
    }
  }
}

extern "C" void kernel_launch(void* const* d_in, const int* in_sizes, int n_in,
                              void* d_out, int out_size, void* d_ws, size_t ws_size,
                              hipStream_t stream) {
  const float* x     = (const float*)d_in[0];
  const float* ref   = (const float*)d_in[1];
  const float* wcd   = (const float*)d_in[2];
  const float* bcd   = (const float*)d_in[3];
  const float* wp    = (const float*)d_in[4];
  const float* bp    = (const float*)d_in[5];
  const float* wm    = (const float*)d_in[6];
  const float* bm    = (const float*)d_in[7];
  const float* wc    = (const float*)d_in[8];
  const float* bc    = (const float*)d_in[9];
  const float* wconv = (const float*)d_in[10];
  float* out = (float*)d_out;

  char* w8 = (char*)d_ws;
  ushort* Wpk     = (ushort*)(w8 + 0);           //    737,280 B
  float*  Bc      = (float*)(w8 + 737280);       //      2,560 B
  ushort* W2pk    = (ushort*)(w8 + 739840);      //     73,728 B
  ushort* fusedt  = (ushort*)(w8 + 813568);      //  8,388,608 B (pixel-major)
  ushort* xtb     = (ushort*)(w8 + 9202176);     //  8,388,608 B -> total 17,590,784 B

  k_merge <<<1440, 256, 0, stream>>>(wp, bp, wm, bm, wc, bc, wconv, Wpk, Bc, W2pk);
  k_fused <<<1024, 256, 0, stream>>>(x, ref, wcd, bcd, fusedt, xtb);
  k_all   <<<1024, 256, 0, stream>>>(Wpk, fusedt, Bc, xtb, W2pk, out);
}

// Round 4
// 244.066 us; speedup vs baseline: 1.1267x; 1.0641x over previous
//
#include <hip/hip_runtime.h>
#include <hip/hip_bf16.h>
#include <math.h>

typedef short s16x8 __attribute__((ext_vector_type(8)));
typedef float f32x4 __attribute__((ext_vector_type(4)));

__device__ inline ushort f2bf(float f) {
  unsigned u = __float_as_uint(f);
  u = (u + 0x7FFF + ((u >> 16) & 1)) >> 16;
  return (ushort)u;
}
__device__ inline float bf2f(ushort u) {
  return __uint_as_float(((unsigned)u) << 16);
}
// packed f32x2 -> bf16x2 RNE (bit-identical to f2bf pair)
__device__ inline unsigned pkbf(float a, float b) {
  __hip_bfloat162 h = __float22bfloat162_rn(make_float2(a, b));
  return *(unsigned*)&h;
}
// bf16 pair unpack from a dword: low half / high half (bit-identical to bf2f)
__device__ inline float bflo(unsigned u) { return __uint_as_float(u << 16); }
__device__ inline float bfhi(unsigned u) { return __uint_as_float(u & 0xffff0000u); }
// fast activations: v_exp_f32 + v_rcp_f32; saturate correctly at +/-inf.
__device__ inline float fast_tanh(float v) {
  float e = __builtin_amdgcn_exp2f(v * 2.8853900817779268f);   // exp(2v)
  return 1.f - 2.f * __builtin_amdgcn_rcpf(e + 1.f);
}
__device__ inline float fast_sigmoid(float v) {
  float e = __builtin_amdgcn_exp2f(v * -1.4426950408889634f);  // exp(-v)
  return __builtin_amdgcn_rcpf(1.f + e);
}

// LDS-only barrier: orders ds ops across waves WITHOUT draining vmcnt (so prefetched
// global loads stay in flight across phase boundaries).
#define LDS_BARRIER()                                          \
  do {                                                         \
    asm volatile("s_waitcnt lgkmcnt(0)" ::: "memory");         \
    __builtin_amdgcn_s_barrier();                              \
  } while (0)

// ---- sigma channel permutation -------------------------------------------------------
// c = [rq m q1 q0 r1 r0] -> sigma(c) = [rq q1 q0 m r1 r0].
// Purpose: the epilogue thread (rowq,quad) owns channels {rq*32+quad*4+r} U
// {rq*32+16+quad*4+r}; in sigma-space these 8 channels are CONTIGUOUS -> one uint4
// gather per corner instead of two uint2. xtb, colT, W2pk all live in sigma-space;
// Wpk/Bc/off-mod stay in original space (epilogue permutes at write time).
__device__ inline int sigma(int c) {
  return (c & 0x20) | ((c & 0x0C) << 1) | ((c & 0x10) >> 2) | (c & 3);
}
__device__ inline int sigma_inv(int d) {
  return (d & 0x20) | ((d & 4) << 2) | ((d & 0x18) >> 1) | (d & 3);
}

// ---- PERMUTED head-row space (640 rows):
//   g in [0,18): off | [18,27): mod | [27,64): pad | [64,640): col j=g-64=k*64+c
//     source col channel cc = c*9+k.
// ---- K1: fused 1x1 conv -> fusedt[pix][64] bf16 + xtb (sigma-space) transpose,
//      PLUS weight packing (former k_merge) on blocks >= 1024 -------------------------
// Wpk[og 5][ks 18][ocq 2][mi 4][lane 64][e 8]; W2pk[ks 18][mi 4][lane 64][e 8].
__global__ __launch_bounds__(256) void k_fused(
    const float* __restrict__ x, const float* __restrict__ ref,
    const float* __restrict__ wcd, const float* __restrict__ bcd,
    const float* __restrict__ wp, const float* __restrict__ bp,
    const float* __restrict__ wm, const float* __restrict__ bm,
    const float* __restrict__ wc, const float* __restrict__ bc,
    const float* __restrict__ wconv,
    ushort* __restrict__ fusedt, ushort* __restrict__ xtb,
    ushort* __restrict__ Wpk, float* __restrict__ Bc, ushort* __restrict__ W2pk) {
  __shared__ float sw[128 * 64];
  __shared__ float sx[64][65];
  __shared__ float sb[64];

  if (blockIdx.x >= 1024) {
    // ---- weight-packing blocks (former k_merge), 1440 blocks ----
    int i = (blockIdx.x - 1024) * 256 + threadIdx.x;
    if (i < 368640) {
      int e = i & 7, lane = (i >> 3) & 63, mi = (i >> 9) & 3, ocq = (i >> 11) & 1;
      int hi = i >> 12;                 // 0..89
      int ks = hi % 18, og = hi / 18;
      int g = og * 128 + ocq * 64 + mi * 16 + (lane & 15);
      int ci = ((ks & 1) << 5) + ((lane >> 4) << 3) + e;
      int kk = ks >> 1;
      int col = ci * 9 + kk;
      float v = 0.f;
      if (g < 18)       v = wp[g * 576 + col];
      else if (g < 27)  v = wm[(g - 18) * 576 + col];
      else if (g >= 64) {
        int j = g - 64;
        int cc = (j & 63) * 9 + (j >> 6);
        v = wc[cc * 576 + col];
      }
      Wpk[i] = f2bf(v);
    }
    if (i < 36864) {
      int e = i & 7, lane = (i >> 3) & 63, mi = (i >> 9) & 3, ks = i >> 11;  // 0..17
      int o = mi * 16 + (lane & 15);
      int p = (ks << 5) + ((lane >> 4) << 3) + e;
      int kk2 = p >> 6, d = p & 63;
      int c = sigma_inv(d);            // W2pk K-order lives in sigma-space
      W2pk[i] = f2bf(wconv[o * 576 + c * 9 + kk2]);
    }
    if (i < 640) {
      float bv = 0.f;
      if (i < 18)       bv = bp[i];
      else if (i < 27)  bv = bm[i - 18];
      else if (i >= 64) {
        int j = i - 64;
        bv = bc[(j & 63) * 9 + (j >> 6)];
      }
      Bc[i] = bv;
    }
    return;
  }

  // ---- fused 1x1 conv blocks ----
  const int t = threadIdx.x;
  for (int i = t; i < 128 * 64; i += 256) {
    int ci = i >> 6, o = i & 63;
    sw[i] = wcd[o * 128 + ci];
  }
  if (t < 64) sb[t] = bcd[t];
  const int b = blockIdx.x >> 8, hw0 = (blockIdx.x & 255) << 6;
  for (int i = t; i < 4096; i += 256) {
    int c = i >> 6, hwi = i & 63;
    sx[c][hwi] = x[((size_t)((b << 6) + c) << 14) + hw0 + hwi];
  }
  __syncthreads();

  // xtb[b][hw][sigma(c)] bf16 pixel-major (sigma preserves bit0 -> pairs stay adjacent)
  for (int i = t * 2; i < 4096; i += 512) {
    int hwi = i >> 6, c = i & 63;    // c even
    unsigned pk = pkbf(sx[c][hwi], sx[c + 1][hwi]);
    *(unsigned*)(xtb + (((size_t)b << 14) + hw0 + hwi) * 64 + sigma(c)) = pk;
  }

  const int pxi = t & 63, oq = t >> 6;      // wave-uniform oq -> LDS broadcast
  const int pix = blockIdx.x * 64 + pxi;
  const float* rb = ref + (((size_t)b << 6) << 14) + hw0 + pxi;

  float4 acc[4];
  #pragma unroll
  for (int q = 0; q < 4; q++)
    acc[q] = *(const float4*)&sb[oq * 16 + 4 * q];

  for (int ci = 0; ci < 64; ci++) {
    float v = sx[ci][pxi];
    const float4* wr = (const float4*)&sw[ci * 64 + oq * 16];
    #pragma unroll
    for (int q = 0; q < 4; q++) {
      float4 w4 = wr[q];
      acc[q].x += w4.x * v; acc[q].y += w4.y * v;
      acc[q].z += w4.z * v; acc[q].w += w4.w * v;
    }
  }
  for (int ci = 0; ci < 64; ci++) {
    float v = rb[(size_t)ci << 14];
    const float4* wr = (const float4*)&sw[(64 + ci) * 64 + oq * 16];
    #pragma unroll
    for (int q = 0; q < 4; q++) {
      float4 w4 = wr[q];
      acc[q].x += w4.x * v; acc[q].y += w4.y * v;
      acc[q].z += w4.z * v; acc[q].w += w4.w * v;
    }
  }
  uint4 o0, o1;
  o0.x = pkbf(acc[0].x, acc[0].y); o0.y = pkbf(acc[0].z, acc[0].w);
  o0.z = pkbf(acc[1].x, acc[1].y); o0.w = pkbf(acc[1].z, acc[1].w);
  o1.x = pkbf(acc[2].x, acc[2].y); o1.y = pkbf(acc[2].z, acc[2].w);
  o1.z = pkbf(acc[3].x, acc[3].y); o1.w = pkbf(acc[3].z, acc[3].w);
  ushort* fb = fusedt + ((size_t)pix << 6) + oq * 16;
  *(uint4*)fb       = o0;
  *(uint4*)(fb + 8) = o1;
}

// ---- K3: FULLY FUSED head-GEMM + sampler + final GEMM, 64-px tiles --------------------
// grid 1024; block 256 = 4 waves; LDS 40,448B -> 4 blocks/CU.
// Round-4: sigma-space gathers -- each epilogue thread's 8 channels are contiguous, so
// bilinear gathers are 8x uint4 per thread per k (was 16x uint2): half the VMEM
// instructions, same cache lines. colT stores sigma-space (1 uint4 write per ni).
__global__ __launch_bounds__(256, 4) void k_all(
    const ushort* __restrict__ Wpk, const ushort* __restrict__ fusedt,
    const float* __restrict__ Bc, const ushort* __restrict__ xtb,
    const ushort* __restrict__ W2pk, float* __restrict__ out) {
  __shared__ __align__(16) ushort sF[3 * 66 * 64];    // 25,344 B
  __shared__ __align__(16) ushort colT[64 * 64];      //  8,192 B
  __shared__ float homT[64 * 27];                     //  6,912 B -> 40,448 B total
  const int t = threadIdx.x;
  const int lane = t & 63, wv = t >> 6;
  const int rowid = blockIdx.x;           // b*256 + h*2 + half
  const int b = rowid >> 8;
  const int rem = rowid & 255;
  const int h = rem >> 1, hf = rem & 1;
  const int w0 = hf << 6;
  const int hw0 = (h << 7) + w0;

  // stage fused rows h-1..h+1, w1 in [0,66) covering gw in [w0-1, w0+64]
  for (int idx = t; idx < 1584; idx += 256) {   // 198 pixels x 8 ci-chunks
    int p = idx >> 3, j = idx & 7;
    int row = p / 66, w1 = p - row * 66;
    int gh = h + row - 1, gw = w0 + w1 - 1;
    uint4 v = make_uint4(0u, 0u, 0u, 0u);
    if (gh >= 0 && gh < 128 && (unsigned)gw < 128u)
      v = *(const uint4*)(fusedt + ((size_t)((b << 14) + (gh << 7) + gw) << 6) + j * 8);
    int slot = (j + w1) & 7;
    *(uint4*)(sF + (p << 6) + slot * 8) = v;
  }

  const int pxq = wv & 1, rowq = wv >> 1;
  const int nif = lane & 15, kb = lane >> 4, quad = lane >> 4;
  const int wlaneoff = lane << 3;                          // element offset in weight row
  const int rfq = __builtin_amdgcn_readfirstlane(rowq);    // wave-uniform -> SGPR
  const int rowel9  = rfq << 9;                            // off/mod af offset (mi=rowq)
  const int rowel10 = rfq << 10;                           // col/final af base
  const int cbase = (rowq << 5) + (quad << 2);             // original-space channel base
  const int tcb   = (rowq << 5) + (quad << 3);             // sigma-space elem base (8 ch)

  // invariant sF read offsets (ushort elements): reused by all 10 head GEMMs
  int sfo[18][2];
  #pragma unroll
  for (int ks = 0; ks < 18; ks++) {
    const int kk = ks >> 1, half = ks & 1;
    const int dr = kk / 3, dc = kk - dr * 3;
    const int gci = half * 4 + kb;
    #pragma unroll
    for (int ni = 0; ni < 2; ni++) {
      const int r = (pxq << 5) + ni * 16 + nif;
      const int w1 = r + dc;
      sfo[ks][ni] = ((dr * 66 + w1) << 6) + (((gci + w1) & 7) << 3);
    }
  }
  // invariant colT read offsets for the final GEMM (sigma-chunk = khalf*4+kb)
  int cto[2][2];
  #pragma unroll
  for (int khalf = 0; khalf < 2; khalf++) {
    const int g0 = (khalf << 2) + kb;
    #pragma unroll
    for (int ni = 0; ni < 2; ni++) {
      const int r = (pxq << 5) + ni * 16 + nif;
      cto[khalf][ni] = (r << 6) + (((g0 + r) & 7) << 3);
    }
  }

  __syncthreads();

  // ---- off/mod GEMM: wave (rowq,pxq) computes rows rowq*16..+16 of its 32 px ----
  {
    f32x4 acc[2];
    acc[0] = (f32x4){0.f, 0.f, 0.f, 0.f};
    acc[1] = (f32x4){0.f, 0.f, 0.f, 0.f};
    #pragma unroll
    for (int ks = 0; ks < 18; ks++) {
      s16x8 af = *(const s16x8*)(Wpk + (ks << 12) + rowel9 + wlaneoff);
      s16x8 b0 = *(const s16x8*)(sF + sfo[ks][0]);
      s16x8 b1 = *(const s16x8*)(sF + sfo[ks][1]);
      acc[0] = __builtin_amdgcn_mfma_f32_16x16x32_bf16(af, b0, acc[0], 0, 0, 0);
      acc[1] = __builtin_amdgcn_mfma_f32_16x16x32_bf16(af, b1, acc[1], 0, 0, 0);
    }
    const float4 b4 = *(const float4*)(Bc + (rowq << 4) + (quad << 2));
    const float bb[4] = {b4.x, b4.y, b4.z, b4.w};
    #pragma unroll
    for (int ni = 0; ni < 2; ni++) {
      const int px = (pxq << 5) + ni * 16 + nif;
      #pragma unroll
      for (int r = 0; r < 4; r++) {
        const int g = (rowq << 4) + (quad << 2) + r;
        float v = acc[ni][r] + bb[r];
        if (g < 18)       homT[px * 27 + g] = v;
        else if (g < 27)  homT[px * 27 + g] = fast_sigmoid(v);
      }
    }
  }

  __syncthreads();   // homT (written by both rowq waves) visible to everyone

  const ushort* xb0 = xtb + ((size_t)b << 20);

  // ---- gather-prefetch state (consumed one iteration later) ----
  float mkv[2];
  float wlv[2][4];
  uint4 gpre[2][4];   // [ni][corner]: 8 contiguous sigma-channels (16B)

  auto prefetch_k = [&](int kk) {
    const int kdr = kk / 3, kdc = kk - kdr * 3;
    #pragma unroll
    for (int ni = 0; ni < 2; ni++) {
      const int px = (pxq << 5) + ni * 16 + nif;
      const int hb = px * 27;
      float ox = homT[hb + kk];
      float oy = homT[hb + 9 + kk];
      mkv[ni] = homT[hb + 18 + kk];
      float px_ = (float)(h + kdr) + ox;
      float py_ = (float)(w0 + px + kdc) + oy;
      float fx = floorf(px_), fy = floorf(py_);
      float qltx = fminf(fmaxf(fx, 0.f), 129.f);
      float qlty = fminf(fmaxf(fy, 0.f), 129.f);
      float qrbx = fminf(fmaxf(fx + 1.f, 0.f), 129.f);
      float qrby = fminf(fmaxf(fy + 1.f, 0.f), 129.f);
      float sx = fminf(fmaxf(px_, 0.f), 129.f);
      float sy = fminf(fmaxf(py_, 0.f), 129.f);
      float ax = 1.f + qltx - sx, bx = 1.f - qrbx + sx;
      float ay = 1.f + qlty - sy, by = 1.f - qrby + sy;
      int iltx = (int)qltx, ilty = (int)qlty, irbx = (int)qrbx, irby = (int)qrby;
      bool vltx = (iltx >= 1) && (iltx <= 128);
      bool vlty = (ilty >= 1) && (ilty <= 128);
      bool vrbx = (irbx >= 1) && (irbx <= 128);
      bool vrby = (irby >= 1) && (irby <= 128);
      float wl[4];
      int   ofs[4];
      wl[0] = (vltx && vlty) ? ax * ay : 0.f;
      wl[1] = (vrbx && vrby) ? bx * by : 0.f;
      wl[2] = (vltx && vrby) ? ax * by : 0.f;
      wl[3] = (vrbx && vlty) ? bx * ay : 0.f;
      ofs[0] = (vltx && vlty) ? ((iltx - 1) << 7) + (ilty - 1) : 0;
      ofs[1] = (vrbx && vrby) ? ((irbx - 1) << 7) + (irby - 1) : 0;
      ofs[2] = (vltx && vrby) ? ((iltx - 1) << 7) + (irby - 1) : 0;
      ofs[3] = (vrbx && vlty) ? ((irbx - 1) << 7) + (ilty - 1) : 0;
      #pragma unroll
      for (int corner = 0; corner < 4; corner++) {
        wlv[ni][corner] = wl[corner];
        gpre[ni][corner] = *(const uint4*)(xb0 + ((size_t)ofs[corner] << 6) + tcb);
      }
    }
  };

  prefetch_k(0);   // loads in flight across col-GEMM(0)

  f32x4 aco[2][2];
  #pragma unroll
  for (int mi = 0; mi < 2; mi++)
    #pragma unroll
    for (int ni = 0; ni < 2; ni++) aco[mi][ni] = (f32x4){0.f, 0.f, 0.f, 0.f};

  s16x8 w2pre[2][2];   // [khalf][mi] final-GEMM fragments, prefetched per k

  #pragma unroll 1
  for (int k = 0; k < 9; k++) {
    // ---- col GEMM for this k: permuted rows 64+k*64 .. 128+k*64 ----
    const int q = 1 + k, og = q >> 1, ocq = q & 1;
    const ushort* wb = Wpk + ((size_t)(((og * 36) + ocq) << 11)) + rowel10 + wlaneoff;
    f32x4 acc[2][2];
    #pragma unroll
    for (int mi = 0; mi < 2; mi++)
      #pragma unroll
      for (int ni = 0; ni < 2; ni++) acc[mi][ni] = (f32x4){0.f, 0.f, 0.f, 0.f};
    __builtin_amdgcn_s_setprio(1);
    #pragma unroll
    for (int ks = 0; ks < 18; ks++) {
      const ushort* wp8 = wb + (ks << 12);
      s16x8 af0 = *(const s16x8*)(wp8);
      s16x8 af1 = *(const s16x8*)(wp8 + 512);
      s16x8 b0 = *(const s16x8*)(sF + sfo[ks][0]);
      s16x8 b1 = *(const s16x8*)(sF + sfo[ks][1]);
      acc[0][0] = __builtin_amdgcn_mfma_f32_16x16x32_bf16(af0, b0, acc[0][0], 0, 0, 0);
      acc[0][1] = __builtin_amdgcn_mfma_f32_16x16x32_bf16(af0, b1, acc[0][1], 0, 0, 0);
      acc[1][0] = __builtin_amdgcn_mfma_f32_16x16x32_bf16(af1, b0, acc[1][0], 0, 0, 0);
      acc[1][1] = __builtin_amdgcn_mfma_f32_16x16x32_bf16(af1, b1, acc[1][1], 0, 0, 0);
    }
    __builtin_amdgcn_s_setprio(0);

    LDS_BARRIER();   // B1: prior final-MFMA colT ds_reads done before overwrite (WAR)

    // ---- epilogue: tanh + prefetched gather + modulate -> colT (sigma-space) ----
    {
      #pragma unroll
      for (int ni = 0; ni < 2; ni++) {
        const int px = (pxq << 5) + ni * 16 + nif;
        const float mk = mkv[ni];
        float pos[2][4];
        #pragma unroll
        for (int mi = 0; mi < 2; mi++)
          #pragma unroll
          for (int r = 0; r < 4; r++) pos[mi][r] = 0.f;
        #pragma unroll
        for (int corner = 0; corner < 4; corner++) {
          uint4 A = gpre[ni][corner];
          float wgt = wlv[ni][corner];
          pos[0][0] += wgt * bflo(A.x); pos[0][1] += wgt * bfhi(A.x);
          pos[0][2] += wgt * bflo(A.y); pos[0][3] += wgt * bfhi(A.y);
          pos[1][0] += wgt * bflo(A.z); pos[1][1] += wgt * bfhi(A.z);
          pos[1][2] += wgt * bflo(A.w); pos[1][3] += wgt * bfhi(A.w);
        }
        float v[2][4];
        #pragma unroll
        for (int mi = 0; mi < 2; mi++) {
          const int c = cbase + mi * 16;
          const float4 b4 = *(const float4*)(Bc + 64 + (k << 6) + c);
          v[mi][0] = (fast_tanh(acc[mi][ni][0] + b4.x) + pos[mi][0]) * mk;
          v[mi][1] = (fast_tanh(acc[mi][ni][1] + b4.y) + pos[mi][1]) * mk;
          v[mi][2] = (fast_tanh(acc[mi][ni][2] + b4.z) + pos[mi][2]) * mk;
          v[mi][3] = (fast_tanh(acc[mi][ni][3] + b4.w) + pos[mi][3]) * mk;
        }
        uint4 ow;
        ow.x = pkbf(v[0][0], v[0][1]);
        ow.y = pkbf(v[0][2], v[0][3]);
        ow.z = pkbf(v[1][0], v[1][1]);
        ow.w = pkbf(v[1][2], v[1][3]);
        const int slot = ((tcb >> 3) + px) & 7;     // sigma-chunk rotation
        *(uint4*)(colT + (px << 6) + slot * 8) = ow;
      }
    }

    // prefetch final-GEMM weight fragments for THIS k (used right after B2)
    #pragma unroll
    for (int khalf = 0; khalf < 2; khalf++) {
      const ushort* w2 = W2pk + (((k << 1) + khalf) << 11) + rowel10 + wlaneoff;
      w2pre[khalf][0] = *(const s16x8*)(w2);
      w2pre[khalf][1] = *(const s16x8*)(w2 + 512);
    }
    // prefetch gathers for k+1 (complete during final-MFMA(k) + col-GEMM(k+1))
    if (k < 8) prefetch_k(k + 1);

    LDS_BARRIER();   // B2: colT writes visible to final MFMA (RAW); vmcnt NOT drained

    // ---- final-GEMM MFMA: 2 ks-steps over this k-tile ----
    __builtin_amdgcn_s_setprio(1);
    #pragma unroll
    for (int khalf = 0; khalf < 2; khalf++) {
      s16x8 b0 = *(const s16x8*)(colT + cto[khalf][0]);
      s16x8 b1 = *(const s16x8*)(colT + cto[khalf][1]);
      aco[0][0] = __builtin_amdgcn_mfma_f32_16x16x32_bf16(w2pre[khalf][0], b0, aco[0][0], 0, 0, 0);
      aco[0][1] = __builtin_amdgcn_mfma_f32_16x16x32_bf16(w2pre[khalf][0], b1, aco[0][1], 0, 0, 0);
      aco[1][0] = __builtin_amdgcn_mfma_f32_16x16x32_bf16(w2pre[khalf][1], b0, aco[1][0], 0, 0, 0);
      aco[1][1] = __builtin_amdgcn_mfma_f32_16x16x32_bf16(w2pre[khalf][1], b1, aco[1][1], 0, 0, 0);
    }
    __builtin_amdgcn_s_setprio(0);
  }

  // ---- store out ----
  #pragma unroll
  for (int mi = 0; mi < 2; mi++) {
    #pragma unroll
    for (int ni = 0; ni < 2; ni++) {
      int hwp = hw0 + (pxq << 5) + ni * 16 + nif;
      #pragma unroll
      for (int r = 0; r < 4; r++) {
        int o = (rowq << 5) + mi * 16 + (quad << 2) + r;
        out[(((size_t)b * 64 + o) << 14) + hwp] = aco[mi][ni][r];
      }
    }
  }
}

extern "C" void kernel_launch(void* const* d_in, const int* in_sizes, int n_in,
                              void* d_out, int out_size, void* d_ws, size_t ws_size,
                              hipStream_t stream) {
  const float* x     = (const float*)d_in[0];
  const float* ref   = (const float*)d_in[1];
  const float* wcd   = (const float*)d_in[2];
  const float* bcd   = (const float*)d_in[3];
  const float* wp    = (const float*)d_in[4];
  const float* bp    = (const float*)d_in[5];
  const float* wm    = (const float*)d_in[6];
  const float* bm    = (const float*)d_in[7];
  const float* wc    = (const float*)d_in[8];
  const float* bc    = (const float*)d_in[9];
  const float* wconv = (const float*)d_in[10];
  float* out = (float*)d_out;

  char* w8 = (char*)d_ws;
  ushort* Wpk     = (ushort*)(w8 + 0);           //    737,280 B
  float*  Bc      = (float*)(w8 + 737280);       //      2,560 B
  ushort* W2pk    = (ushort*)(w8 + 739840);      //     73,728 B
  ushort* fusedt  = (ushort*)(w8 + 813568);      //  8,388,608 B (pixel-major)
  ushort* xtb     = (ushort*)(w8 + 9202176);     //  8,388,608 B -> total 17,590,784 B

  // blocks [0,1024): fused conv + xtb; blocks [1024,2464): weight packing
  k_fused <<<2464, 256, 0, stream>>>(x, ref, wcd, bcd, wp, bp, wm, bm, wc, bc, wconv,
                                     fusedt, xtb, Wpk, Bc, W2pk);
  k_all   <<<1024, 256, 0, stream>>>(Wpk, fusedt, Bc, xtb, W2pk, out);
}